// Round 1
// baseline (1409.190 us; speedup 1.0000x reference)
//
#include <hip/hip_runtime.h>
#include <math.h>

#define N_TOK 4096
#define C_DIM 256

// ---------------------------------------------------------------------------
// QK projection: q[b][n][o] = sum_c Wq[o][c] x[b][c][n] + bq[o]   (o<32)
// block: 256 thr = (32 o, 2 sel(q/k), 4 n-groups of 8)
// grid: B * (4096/32) = 512
// ---------------------------------------------------------------------------
__global__ __launch_bounds__(256) void qk_proj_kernel(
    const float* __restrict__ x,
    const float* __restrict__ Wq, const float* __restrict__ bq,
    const float* __restrict__ Wk, const float* __restrict__ bk,
    float* __restrict__ qg, float* __restrict__ kg)
{
    __shared__ float xs[64 * 32];        // [ci][n]
    __shared__ float wl[2 * 64 * 32];    // [sel][ci][o]
    int b  = blockIdx.x >> 7;
    int n0 = (blockIdx.x & 127) * 32;
    int t  = threadIdx.x;
    int o   = t & 31;
    int sel = (t >> 5) & 1;
    int ng  = t >> 6;                    // 0..3

    float acc[8];
#pragma unroll
    for (int i = 0; i < 8; ++i) acc[i] = 0.f;

    for (int cc = 0; cc < 256; cc += 64) {
        __syncthreads();
        {   // stage x chunk: 64 ci x 32 n
            int ci = t >> 3;
            int n4 = (t & 7) * 4;
#pragma unroll
            for (int rep = 0; rep < 2; ++rep) {
                float4 v4 = *(const float4*)&x[(size_t)(b * 256 + cc + rep * 32 + ci) * N_TOK + n0 + n4];
                *(float4*)&xs[(rep * 32 + ci) * 32 + n4] = v4;
            }
        }
        {   // stage transposed weights
            int oo = t & 31;
            int jg = t >> 5;             // 0..7
#pragma unroll
            for (int jj = 0; jj < 8; ++jj) {
                int ci = jg * 8 + jj;
                wl[0 * 2048 + ci * 32 + oo] = Wq[oo * 256 + cc + ci];
                wl[1 * 2048 + ci * 32 + oo] = Wk[oo * 256 + cc + ci];
            }
        }
        __syncthreads();
        for (int ci = 0; ci < 64; ++ci) {
            float w = wl[sel * 2048 + ci * 32 + o];
            float4 xa = *(const float4*)&xs[ci * 32 + ng * 8];
            float4 xb = *(const float4*)&xs[ci * 32 + ng * 8 + 4];
            acc[0] += w * xa.x; acc[1] += w * xa.y; acc[2] += w * xa.z; acc[3] += w * xa.w;
            acc[4] += w * xb.x; acc[5] += w * xb.y; acc[6] += w * xb.z; acc[7] += w * xb.w;
        }
    }
    float bias = sel ? bk[o] : bq[o];
    float* dst = sel ? kg : qg;
#pragma unroll
    for (int nn = 0; nn < 8; ++nn)
        dst[(size_t)(b * N_TOK + n0 + ng * 8 + nn) * 32 + o] = acc[nn] + bias;
}

// ---------------------------------------------------------------------------
// V projection: v[b][n][c] = sum_ci Wv[c][ci] x[b][ci][n] + bv[c]
// block: 256 thr (thread <-> channel c), covers 32 n.  grid: 512
// ---------------------------------------------------------------------------
__global__ __launch_bounds__(256) void v_proj_kernel(
    const float* __restrict__ x, const float* __restrict__ Wv,
    const float* __restrict__ bv, float* __restrict__ vg)
{
    __shared__ float xs[32 * 32];        // [ci][n]
    __shared__ float wl[32 * 256];       // [ci][c]
    int b  = blockIdx.x >> 7;
    int n0 = (blockIdx.x & 127) * 32;
    int t  = threadIdx.x;                // channel

    float acc[32];
#pragma unroll
    for (int i = 0; i < 32; ++i) acc[i] = 0.f;

    for (int cc = 0; cc < 256; cc += 32) {
        __syncthreads();
        {   // stage x chunk
            int ci = t >> 3;
            int n4 = (t & 7) * 4;
            *(float4*)&xs[ci * 32 + n4] =
                *(const float4*)&x[(size_t)(b * 256 + cc + ci) * N_TOK + n0 + n4];
        }
        {   // stage Wv chunk transposed: each thread reads its own row (contiguous)
#pragma unroll
            for (int j4 = 0; j4 < 8; ++j4) {
                float4 w4 = *(const float4*)&Wv[t * 256 + cc + j4 * 4];
                wl[(j4 * 4 + 0) * 256 + t] = w4.x;
                wl[(j4 * 4 + 1) * 256 + t] = w4.y;
                wl[(j4 * 4 + 2) * 256 + t] = w4.z;
                wl[(j4 * 4 + 3) * 256 + t] = w4.w;
            }
        }
        __syncthreads();
        for (int ci = 0; ci < 32; ++ci) {
            float w = wl[ci * 256 + t];
#pragma unroll
            for (int n4 = 0; n4 < 8; ++n4) {
                float4 xv = *(const float4*)&xs[ci * 32 + n4 * 4];
                acc[n4 * 4 + 0] += w * xv.x;
                acc[n4 * 4 + 1] += w * xv.y;
                acc[n4 * 4 + 2] += w * xv.z;
                acc[n4 * 4 + 3] += w * xv.w;
            }
        }
    }
    float bias = bv[t];
    for (int nn = 0; nn < 32; ++nn)
        vg[(size_t)(b * N_TOK + n0 + nn) * 256 + t] = acc[nn] + bias;
}

// ---------------------------------------------------------------------------
// Flash attention: per block = 1 batch x 32-query tile. Online softmax.
// thread: qi = t&31 (query), cb = t>>5 (32-channel block of V/out)
// att written as (B, C, N) for the conv.
// ---------------------------------------------------------------------------
__global__ __launch_bounds__(256) void flash_kernel(
    const float* __restrict__ qg, const float* __restrict__ kg,
    const float* __restrict__ vg, float* __restrict__ att)
{
    __shared__ float k_lds[32 * 32];     // [m][d]
    __shared__ float v_lds[32 * 256];    // [m][c]
    __shared__ float s_lds[32 * 33];     // [m][qi] (+1 pad)
    int b  = blockIdx.x >> 7;
    int n0 = (blockIdx.x & 127) * 32;
    int t  = threadIdx.x;
    int qi = t & 31;
    int cb = t >> 5;                     // 0..7
    const float scale = 0.17677669529663687f;   // 1/sqrt(32)

    float qreg[32];
#pragma unroll
    for (int j4 = 0; j4 < 8; ++j4) {
        float4 qv = *(const float4*)&qg[(size_t)(b * N_TOK + n0 + qi) * 32 + j4 * 4];
        qreg[j4 * 4 + 0] = qv.x; qreg[j4 * 4 + 1] = qv.y;
        qreg[j4 * 4 + 2] = qv.z; qreg[j4 * 4 + 3] = qv.w;
    }
    float acc[32];
#pragma unroll
    for (int i = 0; i < 32; ++i) acc[i] = 0.f;
    float Mr = -3.0e38f, Lr = 0.f;

    for (int m0 = 0; m0 < N_TOK; m0 += 32) {
        __syncthreads();                 // protect LDS from prev iteration readers
        {   // stage K tile (32x32)
            int mm = t >> 3, d4 = (t & 7) * 4;
            *(float4*)&k_lds[mm * 32 + d4] =
                *(const float4*)&kg[(size_t)(b * N_TOK + m0 + mm) * 32 + d4];
        }
        {   // stage V tile (32 keys x 256 ch) - rows contiguous in (B,N,C) layout
#pragma unroll
            for (int r = 0; r < 8; ++r) {
                int f4i = t + r * 256;   // 0..2047
                *(float4*)&v_lds[f4i * 4] =
                    *(const float4*)&vg[(size_t)(b * N_TOK + m0) * 256 + f4i * 4];
            }
        }
        __syncthreads();
        // S = scale * q . k  ; thread computes m = cb*4 .. cb*4+3 for its qi
#pragma unroll
        for (int jj = 0; jj < 4; ++jj) {
            int m = cb * 4 + jj;
            float s = 0.f;
#pragma unroll
            for (int d4 = 0; d4 < 8; ++d4) {
                float4 kv = *(const float4*)&k_lds[m * 32 + d4 * 4];
                s += qreg[d4 * 4 + 0] * kv.x + qreg[d4 * 4 + 1] * kv.y +
                     qreg[d4 * 4 + 2] * kv.z + qreg[d4 * 4 + 3] * kv.w;
            }
            s_lds[m * 33 + qi] = s * scale;
        }
        __syncthreads();
        // online softmax (each thread redundantly processes its qi's row)
        float tmax = -3.0e38f;
#pragma unroll
        for (int m = 0; m < 32; ++m) tmax = fmaxf(tmax, s_lds[m * 33 + qi]);
        float newM = fmaxf(Mr, tmax);
        float corr = __expf(Mr - newM);
#pragma unroll
        for (int i = 0; i < 32; ++i) acc[i] *= corr;
        Lr *= corr;
        float psum = 0.f;
        for (int m = 0; m < 32; ++m) {
            float pm = __expf(s_lds[m * 33 + qi] - newM);
            psum += pm;
#pragma unroll
            for (int j4 = 0; j4 < 8; ++j4) {
                float4 vv = *(const float4*)&v_lds[m * 256 + cb * 32 + j4 * 4];
                acc[j4 * 4 + 0] += pm * vv.x;
                acc[j4 * 4 + 1] += pm * vv.y;
                acc[j4 * 4 + 2] += pm * vv.z;
                acc[j4 * 4 + 3] += pm * vv.w;
            }
        }
        Lr += psum;
        Mr = newM;
    }
    float inv = 1.f / Lr;
#pragma unroll
    for (int j = 0; j < 32; ++j)
        att[(size_t)(b * 256 + cb * 32 + j) * N_TOK + n0 + qi] = acc[j] * inv;
}

// ---------------------------------------------------------------------------
// 3x3 conv + bias + BN(inference) + ReLU + residual
// block: 256 thr = 16x16 pixels; 16 output channels; input chunked by 16 ch
// grid: B * 16 oblk * 16 sp = 1024
// ---------------------------------------------------------------------------
__global__ __launch_bounds__(256) void conv_kernel(
    const float* __restrict__ att, const float* __restrict__ Wo,
    const float* __restrict__ bo,  const float* __restrict__ gamma,
    const float* __restrict__ beta, const float* __restrict__ mean,
    const float* __restrict__ var, const float* __restrict__ x,
    float* __restrict__ out)
{
    __shared__ float in_lds[16 * 324];   // [c][18][18]
    __shared__ float w_lds[16 * 16 * 12];// [c][o][kk(pad12)]
    int blk = blockIdx.x;
    int sp = blk & 15, ob = (blk >> 4) & 15, b = blk >> 8;
    int y0 = (sp >> 2) * 16, x0 = (sp & 3) * 16;
    int o0 = ob * 16;
    int t = threadIdx.x;
    int xx = t & 15, yy = t >> 4;

    float acc[16];
#pragma unroll
    for (int i = 0; i < 16; ++i) acc[i] = 0.f;

    for (int cc = 0; cc < 256; cc += 16) {
        __syncthreads();
        for (int j = t; j < 16 * 324; j += 256) {
            int c = j / 324; int r = j - c * 324;
            int iy = r / 18; int ix = r - iy * 18;
            int gy = y0 - 1 + iy, gx = x0 - 1 + ix;
            float val = 0.f;
            if (gy >= 0 && gy < 64 && gx >= 0 && gx < 64)
                val = att[(size_t)(b * 256 + cc + c) * 4096 + gy * 64 + gx];
            in_lds[j] = val;
        }
        for (int j = t; j < 16 * 144; j += 256) {
            int o = j / 144; int r = j - o * 144;
            int c = r / 9;  int kk = r - c * 9;
            w_lds[c * 192 + o * 12 + kk] = Wo[(size_t)(o0 + o) * 2304 + (cc + c) * 9 + kk];
        }
        __syncthreads();
        for (int c = 0; c < 16; ++c) {
            const float* ip = &in_lds[c * 324 + yy * 18 + xx];
            float a00 = ip[0],  a01 = ip[1],  a02 = ip[2];
            float a10 = ip[18], a11 = ip[19], a12 = ip[20];
            float a20 = ip[36], a21 = ip[37], a22 = ip[38];
#pragma unroll
            for (int o = 0; o < 16; ++o) {
                const float* wp = &w_lds[c * 192 + o * 12];
                float4 wa = *(const float4*)wp;
                float4 wb = *(const float4*)(wp + 4);
                float w8 = wp[8];
                acc[o] += wa.x * a00 + wa.y * a01 + wa.z * a02
                        + wa.w * a10 + wb.x * a11 + wb.y * a12
                        + wb.z * a20 + wb.w * a21 + w8 * a22;
            }
        }
    }
#pragma unroll
    for (int o = 0; o < 16; ++o) {
        int oc = o0 + o;
        float inv = gamma[oc] * rsqrtf(var[oc] + 1e-5f);
        float sh  = (bo[oc] - mean[oc]) * inv + beta[oc];
        float yv  = acc[o] * inv + sh;
        yv = fmaxf(yv, 0.f);
        size_t idx = (size_t)(b * 256 + oc) * 4096 + (size_t)(y0 + yy) * 64 + (x0 + xx);
        out[idx] = yv + x[idx];
    }
}

// ---------------------------------------------------------------------------
extern "C" void kernel_launch(void* const* d_in, const int* in_sizes, int n_in,
                              void* d_out, int out_size, void* d_ws, size_t ws_size,
                              hipStream_t stream)
{
    const float* x  = (const float*)d_in[0];
    const float* Wq = (const float*)d_in[1];
    const float* bq = (const float*)d_in[2];
    const float* Wk = (const float*)d_in[3];
    const float* bk = (const float*)d_in[4];
    const float* Wv = (const float*)d_in[5];
    const float* bv = (const float*)d_in[6];
    const float* Wo = (const float*)d_in[7];
    const float* bo = (const float*)d_in[8];
    const float* gm = (const float*)d_in[9];
    const float* bt = (const float*)d_in[10];
    const float* mn = (const float*)d_in[11];
    const float* vr = (const float*)d_in[12];
    float* out = (float*)d_out;
    float* ws  = (float*)d_ws;

    float* q   = ws;                       //  524288 f
    float* k   = ws + 524288;              //  524288 f
    float* v   = ws + 1048576;             // 4194304 f
    float* att = ws + 1048576 + 4194304;   // 4194304 f   (total ~36 MB)

    qk_proj_kernel<<<512, 256, 0, stream>>>(x, Wq, bq, Wk, bk, q, k);
    v_proj_kernel <<<512, 256, 0, stream>>>(x, Wv, bv, v);
    flash_kernel  <<<512, 256, 0, stream>>>(q, k, v, att);
    conv_kernel   <<<1024, 256, 0, stream>>>(att, Wo, bo, gm, bt, mn, vr, x, out);
}

// Round 2
// 752.330 us; speedup vs baseline: 1.8731x; 1.8731x over previous
//
#include <hip/hip_runtime.h>
#include <hip/hip_bf16.h>
#include <math.h>

#define N_TOK 4096
#define C_DIM 256

typedef __attribute__((ext_vector_type(8))) short short8;
typedef __attribute__((ext_vector_type(4))) float f32x4;

#define MFMA16(a, b, c) __builtin_amdgcn_mfma_f32_16x16x32_bf16(a, b, c, 0, 0, 0)

__device__ inline unsigned pack_bf16x2(float a, float b) {
    __hip_bfloat16 ha = __float2bfloat16(a), hb = __float2bfloat16(b);
    unsigned short ua = *(unsigned short*)&ha, ub = *(unsigned short*)&hb;
    return (unsigned)ua | ((unsigned)ub << 16);
}

// ---------------------------------------------------------------------------
// QK projection -> bf16 (B,N,32) for q and k
// ---------------------------------------------------------------------------
__global__ __launch_bounds__(256) void qk_proj_kernel(
    const float* __restrict__ x,
    const float* __restrict__ Wq, const float* __restrict__ bq,
    const float* __restrict__ Wk, const float* __restrict__ bk,
    __hip_bfloat16* __restrict__ qg, __hip_bfloat16* __restrict__ kg)
{
    __shared__ float xs[64 * 32];
    __shared__ float wl[2 * 64 * 32];
    int b  = blockIdx.x >> 7;
    int n0 = (blockIdx.x & 127) * 32;
    int t  = threadIdx.x;
    int o   = t & 31;
    int sel = (t >> 5) & 1;
    int ng  = t >> 6;

    float acc[8];
#pragma unroll
    for (int i = 0; i < 8; ++i) acc[i] = 0.f;

    for (int cc = 0; cc < 256; cc += 64) {
        __syncthreads();
        {
            int ci = t >> 3;
            int n4 = (t & 7) * 4;
#pragma unroll
            for (int rep = 0; rep < 2; ++rep) {
                float4 v4 = *(const float4*)&x[(size_t)(b * 256 + cc + rep * 32 + ci) * N_TOK + n0 + n4];
                *(float4*)&xs[(rep * 32 + ci) * 32 + n4] = v4;
            }
        }
        {
            int oo = t & 31;
            int jg = t >> 5;
#pragma unroll
            for (int jj = 0; jj < 8; ++jj) {
                int ci = jg * 8 + jj;
                wl[0 * 2048 + ci * 32 + oo] = Wq[oo * 256 + cc + ci];
                wl[1 * 2048 + ci * 32 + oo] = Wk[oo * 256 + cc + ci];
            }
        }
        __syncthreads();
        for (int ci = 0; ci < 64; ++ci) {
            float w = wl[sel * 2048 + ci * 32 + o];
            float4 xa = *(const float4*)&xs[ci * 32 + ng * 8];
            float4 xb = *(const float4*)&xs[ci * 32 + ng * 8 + 4];
            acc[0] += w * xa.x; acc[1] += w * xa.y; acc[2] += w * xa.z; acc[3] += w * xa.w;
            acc[4] += w * xb.x; acc[5] += w * xb.y; acc[6] += w * xb.z; acc[7] += w * xb.w;
        }
    }
    float bias = sel ? bk[o] : bq[o];
    __hip_bfloat16* dst = sel ? kg : qg;
#pragma unroll
    for (int nn = 0; nn < 8; ++nn)
        dst[(size_t)(b * N_TOK + n0 + ng * 8 + nn) * 32 + o] = __float2bfloat16(acc[nn] + bias);
}

// ---------------------------------------------------------------------------
// V projection -> bf16 (B,C,N)  (channel-major rows = V^T tiles for flash)
// ---------------------------------------------------------------------------
__global__ __launch_bounds__(256) void v_proj_kernel(
    const float* __restrict__ x, const float* __restrict__ Wv,
    const float* __restrict__ bv, __hip_bfloat16* __restrict__ vg)
{
    __shared__ float xs[32 * 32];
    __shared__ float wl[32 * 256];
    int b  = blockIdx.x >> 7;
    int n0 = (blockIdx.x & 127) * 32;
    int t  = threadIdx.x;

    float acc[32];
#pragma unroll
    for (int i = 0; i < 32; ++i) acc[i] = 0.f;

    for (int cc = 0; cc < 256; cc += 32) {
        __syncthreads();
        {
            int ci = t >> 3;
            int n4 = (t & 7) * 4;
            *(float4*)&xs[ci * 32 + n4] =
                *(const float4*)&x[(size_t)(b * 256 + cc + ci) * N_TOK + n0 + n4];
        }
        {
#pragma unroll
            for (int j4 = 0; j4 < 8; ++j4) {
                float4 w4 = *(const float4*)&Wv[t * 256 + cc + j4 * 4];
                wl[(j4 * 4 + 0) * 256 + t] = w4.x;
                wl[(j4 * 4 + 1) * 256 + t] = w4.y;
                wl[(j4 * 4 + 2) * 256 + t] = w4.z;
                wl[(j4 * 4 + 3) * 256 + t] = w4.w;
            }
        }
        __syncthreads();
        for (int ci = 0; ci < 32; ++ci) {
            float w = wl[ci * 256 + t];
#pragma unroll
            for (int n4 = 0; n4 < 8; ++n4) {
                float4 xv = *(const float4*)&xs[ci * 32 + n4 * 4];
                acc[n4 * 4 + 0] += w * xv.x;
                acc[n4 * 4 + 1] += w * xv.y;
                acc[n4 * 4 + 2] += w * xv.z;
                acc[n4 * 4 + 3] += w * xv.w;
            }
        }
    }
    float bias = bv[t];
    __hip_bfloat16* drow = &vg[(size_t)(b * 256 + t) * N_TOK + n0];
#pragma unroll
    for (int g = 0; g < 4; ++g) {
        uint4 u;
        u.x = pack_bf16x2(acc[g * 8 + 0] + bias, acc[g * 8 + 1] + bias);
        u.y = pack_bf16x2(acc[g * 8 + 2] + bias, acc[g * 8 + 3] + bias);
        u.z = pack_bf16x2(acc[g * 8 + 4] + bias, acc[g * 8 + 5] + bias);
        u.w = pack_bf16x2(acc[g * 8 + 6] + bias, acc[g * 8 + 7] + bias);
        *(uint4*)&drow[g * 8] = u;
    }
}

// ---------------------------------------------------------------------------
// MFMA flash attention.
// Block: 512 thr = 8 waves; QBLK=64 (4 q-tiles of 16), KVBLK=64.
// Waves 0-3: S^T = mfma(K_tile, Q^T) for q-tile w, online softmax, P->LDS bf16.
// All waves: stage V^T tile (B,C,N rows) into LDS; PV: wave owns 32 channels,
//   acc^T[c][q] += mfma(V^T_frag, P_frag). att written f32 (B,C,N).
// ---------------------------------------------------------------------------
__global__ __launch_bounds__(512) void flash_mfma_kernel(
    const __hip_bfloat16* __restrict__ qg, const __hip_bfloat16* __restrict__ kg,
    const __hip_bfloat16* __restrict__ vg, float* __restrict__ att)
{
    __shared__ __hip_bfloat16 v_lds[256 * 72];   // [c][key] stride 72 (144B)
    __shared__ __hip_bfloat16 p_lds[64 * 72];    // [q][key]  stride 72
    __shared__ float corr_lds[64];
    __shared__ float l_lds[64];

    int b  = blockIdx.x >> 6;
    int n0 = (blockIdx.x & 63) * 64;
    int t  = threadIdx.x;
    int w  = t >> 6, lane = t & 63;
    int l15 = lane & 15, l4 = lane >> 4;
    int qs = w & 3;
    int cw = w * 32;

    const float SC = 0.17677669529663687f * 1.4426950408889634f; // scale*log2(e)

    // Q B-frag: B[d][q], q = l15, d = l4*8+j (contiguous 8 bf16)
    short8 qf = *(const short8*)&qg[((size_t)(b * N_TOK + n0 + qs * 16 + l15)) * 32 + l4 * 8];

    f32x4 zf = {0.f, 0.f, 0.f, 0.f};
    f32x4 acc[4][2];
#pragma unroll
    for (int i = 0; i < 4; ++i) { acc[i][0] = zf; acc[i][1] = zf; }
    float Mr = -3.0e38f, Lr = 0.f;

    for (int m0 = 0; m0 < N_TOK; m0 += 64) {
        // ---- stage V^T tile: thread -> row c = t>>1, half = t&1 (64B each)
        {
            int c = t >> 1, half = t & 1;
            const __hip_bfloat16* src = &vg[((size_t)(b * 256 + c)) * N_TOK + m0 + half * 32];
            __hip_bfloat16* dstp = &v_lds[c * 72 + half * 32];
            short8 s0 = *(const short8*)(src);
            short8 s1 = *(const short8*)(src + 8);
            short8 s2 = *(const short8*)(src + 16);
            short8 s3 = *(const short8*)(src + 24);
            *(short8*)(dstp)      = s0;
            *(short8*)(dstp + 8)  = s1;
            *(short8*)(dstp + 16) = s2;
            *(short8*)(dstp + 24) = s3;
        }

        if (w < 4) {
            // ---- S^T via MFMA: A = K tile (row=key, k=d), B = Q^T
            f32x4 sf[4];
#pragma unroll
            for (int kt = 0; kt < 4; ++kt) {
                short8 kf = *(const short8*)&kg[((size_t)(b * N_TOK + m0 + kt * 16 + l15)) * 32 + l4 * 8];
                sf[kt] = MFMA16(kf, qf, zf);
            }
            // ---- online softmax for q = l15 (keys spread over l4 groups & regs)
            float smax = -3.0e38f;
#pragma unroll
            for (int kt = 0; kt < 4; ++kt)
#pragma unroll
                for (int r = 0; r < 4; ++r) smax = fmaxf(smax, sf[kt][r]);
            smax = fmaxf(smax, __shfl_xor(smax, 16));
            smax = fmaxf(smax, __shfl_xor(smax, 32));
            float newM = fmaxf(Mr, smax);
            float corr = exp2f((Mr - newM) * SC);
            float psum = 0.f;
            float pm[16];
#pragma unroll
            for (int kt = 0; kt < 4; ++kt)
#pragma unroll
                for (int r = 0; r < 4; ++r) {
                    float p = exp2f((sf[kt][r] - newM) * SC);
                    pm[kt * 4 + r] = p;
                    psum += p;
                }
            psum += __shfl_xor(psum, 16);
            psum += __shfl_xor(psum, 32);
            Lr = Lr * corr + psum;
            Mr = newM;
            // ---- P -> LDS (bf16), keys kt*16 + l4*4 + r at row q
#pragma unroll
            for (int kt = 0; kt < 4; ++kt) {
                uint2 u;
                u.x = pack_bf16x2(pm[kt * 4 + 0], pm[kt * 4 + 1]);
                u.y = pack_bf16x2(pm[kt * 4 + 2], pm[kt * 4 + 3]);
                *(uint2*)&p_lds[(qs * 16 + l15) * 72 + kt * 16 + l4 * 4] = u;
            }
            if (l4 == 0) corr_lds[qs * 16 + l15] = corr;
        }
        __syncthreads();

        // ---- PV: A-frags (V^T) cached in regs, reused across all 4 q-tiles
        short8 vfr[2][2];
#pragma unroll
        for (int ct = 0; ct < 2; ++ct)
#pragma unroll
            for (int ks = 0; ks < 2; ++ks)
                vfr[ct][ks] = *(const short8*)&v_lds[(cw + ct * 16 + l15) * 72 + ks * 32 + l4 * 8];

#pragma unroll
        for (int qt = 0; qt < 4; ++qt) {
            float cq = corr_lds[qt * 16 + l15];
#pragma unroll
            for (int ct = 0; ct < 2; ++ct)
#pragma unroll
                for (int r = 0; r < 4; ++r) acc[qt][ct][r] *= cq;
#pragma unroll
            for (int ks = 0; ks < 2; ++ks) {
                short8 bf = *(const short8*)&p_lds[(qt * 16 + l15) * 72 + ks * 32 + l4 * 8];
                acc[qt][0] = MFMA16(vfr[0][ks], bf, acc[qt][0]);
                acc[qt][1] = MFMA16(vfr[1][ks], bf, acc[qt][1]);
            }
        }
        __syncthreads();
    }

    if (w < 4 && l4 == 0) l_lds[qs * 16 + l15] = Lr;
    __syncthreads();

#pragma unroll
    for (int qt = 0; qt < 4; ++qt) {
        float inv = 1.f / l_lds[qt * 16 + l15];
#pragma unroll
        for (int ct = 0; ct < 2; ++ct)
#pragma unroll
            for (int r = 0; r < 4; ++r) {
                int c = cw + ct * 16 + l4 * 4 + r;
                att[((size_t)(b * 256 + c)) * N_TOK + n0 + qt * 16 + l15] = acc[qt][ct][r] * inv;
            }
    }
}

// ---------------------------------------------------------------------------
// 3x3 conv + bias + BN(inference) + ReLU + residual (f32, reads att (B,C,N))
// ---------------------------------------------------------------------------
__global__ __launch_bounds__(256) void conv_kernel(
    const float* __restrict__ att, const float* __restrict__ Wo,
    const float* __restrict__ bo,  const float* __restrict__ gamma,
    const float* __restrict__ beta, const float* __restrict__ mean,
    const float* __restrict__ var, const float* __restrict__ x,
    float* __restrict__ out)
{
    __shared__ float in_lds[16 * 324];
    __shared__ float w_lds[16 * 16 * 12];
    int blk = blockIdx.x;
    int sp = blk & 15, ob = (blk >> 4) & 15, b = blk >> 8;
    int y0 = (sp >> 2) * 16, x0 = (sp & 3) * 16;
    int o0 = ob * 16;
    int t = threadIdx.x;
    int xx = t & 15, yy = t >> 4;

    float acc[16];
#pragma unroll
    for (int i = 0; i < 16; ++i) acc[i] = 0.f;

    for (int cc = 0; cc < 256; cc += 16) {
        __syncthreads();
        for (int j = t; j < 16 * 324; j += 256) {
            int c = j / 324; int r = j - c * 324;
            int iy = r / 18; int ix = r - iy * 18;
            int gy = y0 - 1 + iy, gx = x0 - 1 + ix;
            float val = 0.f;
            if (gy >= 0 && gy < 64 && gx >= 0 && gx < 64)
                val = att[(size_t)(b * 256 + cc + c) * 4096 + gy * 64 + gx];
            in_lds[j] = val;
        }
        for (int j = t; j < 16 * 144; j += 256) {
            int o = j / 144; int r = j - o * 144;
            int c = r / 9;  int kk = r - c * 9;
            w_lds[c * 192 + o * 12 + kk] = Wo[(size_t)(o0 + o) * 2304 + (cc + c) * 9 + kk];
        }
        __syncthreads();
        for (int c = 0; c < 16; ++c) {
            const float* ip = &in_lds[c * 324 + yy * 18 + xx];
            float a00 = ip[0],  a01 = ip[1],  a02 = ip[2];
            float a10 = ip[18], a11 = ip[19], a12 = ip[20];
            float a20 = ip[36], a21 = ip[37], a22 = ip[38];
#pragma unroll
            for (int o = 0; o < 16; ++o) {
                const float* wp = &w_lds[c * 192 + o * 12];
                float4 wa = *(const float4*)wp;
                float4 wb = *(const float4*)(wp + 4);
                float w8 = wp[8];
                acc[o] += wa.x * a00 + wa.y * a01 + wa.z * a02
                        + wa.w * a10 + wb.x * a11 + wb.y * a12
                        + wb.z * a20 + wb.w * a21 + w8 * a22;
            }
        }
    }
#pragma unroll
    for (int o = 0; o < 16; ++o) {
        int oc = o0 + o;
        float inv = gamma[oc] * rsqrtf(var[oc] + 1e-5f);
        float sh  = (bo[oc] - mean[oc]) * inv + beta[oc];
        float yv  = acc[o] * inv + sh;
        yv = fmaxf(yv, 0.f);
        size_t idx = (size_t)(b * 256 + oc) * 4096 + (size_t)(y0 + yy) * 64 + (x0 + xx);
        out[idx] = yv + x[idx];
    }
}

// ---------------------------------------------------------------------------
extern "C" void kernel_launch(void* const* d_in, const int* in_sizes, int n_in,
                              void* d_out, int out_size, void* d_ws, size_t ws_size,
                              hipStream_t stream)
{
    const float* x  = (const float*)d_in[0];
    const float* Wq = (const float*)d_in[1];
    const float* bq = (const float*)d_in[2];
    const float* Wk = (const float*)d_in[3];
    const float* bk = (const float*)d_in[4];
    const float* Wv = (const float*)d_in[5];
    const float* bv = (const float*)d_in[6];
    const float* Wo = (const float*)d_in[7];
    const float* bo = (const float*)d_in[8];
    const float* gm = (const float*)d_in[9];
    const float* bt = (const float*)d_in[10];
    const float* mn = (const float*)d_in[11];
    const float* vr = (const float*)d_in[12];
    float* out = (float*)d_out;

    char* wsb = (char*)d_ws;
    __hip_bfloat16* qg = (__hip_bfloat16*)(wsb);                    // 1 MB
    __hip_bfloat16* kg = (__hip_bfloat16*)(wsb + (1u << 20));       // 1 MB
    __hip_bfloat16* vg = (__hip_bfloat16*)(wsb + (2u << 20));       // 8 MB
    float*          att = (float*)(wsb + (10u << 20));              // 16 MB

    qk_proj_kernel  <<<512,  256, 0, stream>>>(x, Wq, bq, Wk, bk, qg, kg);
    v_proj_kernel   <<<512,  256, 0, stream>>>(x, Wv, bv, vg);
    flash_mfma_kernel<<<256, 512, 0, stream>>>(qg, kg, vg, att);
    conv_kernel     <<<1024, 256, 0, stream>>>(att, Wo, bo, gm, bt, mn, vr, x, out);
}

// Round 3
// 250.298 us; speedup vs baseline: 5.6300x; 3.0057x over previous
//
#include <hip/hip_runtime.h>
#include <hip/hip_bf16.h>
#include <math.h>

#define N_TOK 4096
#define C_DIM 256

typedef __attribute__((ext_vector_type(8))) short short8;
typedef __attribute__((ext_vector_type(4))) float f32x4;

#define MFMA16(a, b, c) __builtin_amdgcn_mfma_f32_16x16x32_bf16(a, b, c, 0, 0, 0)

__device__ inline unsigned pack_bf16x2(float a, float b) {
    __hip_bfloat16 ha = __float2bfloat16(a), hb = __float2bfloat16(b);
    unsigned short ua = *(unsigned short*)&ha, ub = *(unsigned short*)&hb;
    return (unsigned)ua | ((unsigned)ub << 16);
}

// swizzled 16B-chunk slot for row-stride-64B LDS tiles (<=2-way conflicts)
__device__ inline int swz4(int h, int row) { return (h ^ row ^ (row >> 2)) & 3; }

// ---------------------------------------------------------------------------
// QK projection -> bf16 (B,N,32) for q and k
// ---------------------------------------------------------------------------
__global__ __launch_bounds__(256) void qk_proj_kernel(
    const float* __restrict__ x,
    const float* __restrict__ Wq, const float* __restrict__ bq,
    const float* __restrict__ Wk, const float* __restrict__ bk,
    __hip_bfloat16* __restrict__ qg, __hip_bfloat16* __restrict__ kg)
{
    __shared__ float xs[64 * 32];
    __shared__ float wl[2 * 64 * 32];
    int b  = blockIdx.x >> 7;
    int n0 = (blockIdx.x & 127) * 32;
    int t  = threadIdx.x;
    int o   = t & 31;
    int sel = (t >> 5) & 1;
    int ng  = t >> 6;

    float acc[8];
#pragma unroll
    for (int i = 0; i < 8; ++i) acc[i] = 0.f;

    for (int cc = 0; cc < 256; cc += 64) {
        __syncthreads();
        {
            int ci = t >> 3;
            int n4 = (t & 7) * 4;
#pragma unroll
            for (int rep = 0; rep < 2; ++rep) {
                float4 v4 = *(const float4*)&x[(size_t)(b * 256 + cc + rep * 32 + ci) * N_TOK + n0 + n4];
                *(float4*)&xs[(rep * 32 + ci) * 32 + n4] = v4;
            }
        }
        {
            int oo = t & 31;
            int jg = t >> 5;
#pragma unroll
            for (int jj = 0; jj < 8; ++jj) {
                int ci = jg * 8 + jj;
                wl[0 * 2048 + ci * 32 + oo] = Wq[oo * 256 + cc + ci];
                wl[1 * 2048 + ci * 32 + oo] = Wk[oo * 256 + cc + ci];
            }
        }
        __syncthreads();
        for (int ci = 0; ci < 64; ++ci) {
            float w = wl[sel * 2048 + ci * 32 + o];
            float4 xa = *(const float4*)&xs[ci * 32 + ng * 8];
            float4 xb = *(const float4*)&xs[ci * 32 + ng * 8 + 4];
            acc[0] += w * xa.x; acc[1] += w * xa.y; acc[2] += w * xa.z; acc[3] += w * xa.w;
            acc[4] += w * xb.x; acc[5] += w * xb.y; acc[6] += w * xb.z; acc[7] += w * xb.w;
        }
    }
    float bias = sel ? bk[o] : bq[o];
    __hip_bfloat16* dst = sel ? kg : qg;
#pragma unroll
    for (int nn = 0; nn < 8; ++nn)
        dst[(size_t)(b * N_TOK + n0 + ng * 8 + nn) * 32 + o] = __float2bfloat16(acc[nn] + bias);
}

// ---------------------------------------------------------------------------
// V projection -> bf16 (B,C,N)
// ---------------------------------------------------------------------------
__global__ __launch_bounds__(256) void v_proj_kernel(
    const float* __restrict__ x, const float* __restrict__ Wv,
    const float* __restrict__ bv, __hip_bfloat16* __restrict__ vg)
{
    __shared__ float xs[32 * 32];
    __shared__ float wl[32 * 256];
    int b  = blockIdx.x >> 7;
    int n0 = (blockIdx.x & 127) * 32;
    int t  = threadIdx.x;

    float acc[32];
#pragma unroll
    for (int i = 0; i < 32; ++i) acc[i] = 0.f;

    for (int cc = 0; cc < 256; cc += 32) {
        __syncthreads();
        {
            int ci = t >> 3;
            int n4 = (t & 7) * 4;
            *(float4*)&xs[ci * 32 + n4] =
                *(const float4*)&x[(size_t)(b * 256 + cc + ci) * N_TOK + n0 + n4];
        }
        {
#pragma unroll
            for (int j4 = 0; j4 < 8; ++j4) {
                float4 w4 = *(const float4*)&Wv[t * 256 + cc + j4 * 4];
                wl[(j4 * 4 + 0) * 256 + t] = w4.x;
                wl[(j4 * 4 + 1) * 256 + t] = w4.y;
                wl[(j4 * 4 + 2) * 256 + t] = w4.z;
                wl[(j4 * 4 + 3) * 256 + t] = w4.w;
            }
        }
        __syncthreads();
        for (int ci = 0; ci < 32; ++ci) {
            float w = wl[ci * 256 + t];
#pragma unroll
            for (int n4 = 0; n4 < 8; ++n4) {
                float4 xv = *(const float4*)&xs[ci * 32 + n4 * 4];
                acc[n4 * 4 + 0] += w * xv.x;
                acc[n4 * 4 + 1] += w * xv.y;
                acc[n4 * 4 + 2] += w * xv.z;
                acc[n4 * 4 + 3] += w * xv.w;
            }
        }
    }
    float bias = bv[t];
    __hip_bfloat16* drow = &vg[(size_t)(b * 256 + t) * N_TOK + n0];
#pragma unroll
    for (int g = 0; g < 4; ++g) {
        uint4 u;
        u.x = pack_bf16x2(acc[g * 8 + 0] + bias, acc[g * 8 + 1] + bias);
        u.y = pack_bf16x2(acc[g * 8 + 2] + bias, acc[g * 8 + 3] + bias);
        u.z = pack_bf16x2(acc[g * 8 + 4] + bias, acc[g * 8 + 5] + bias);
        u.w = pack_bf16x2(acc[g * 8 + 6] + bias, acc[g * 8 + 7] + bias);
        *(uint4*)&drow[g * 8] = u;
    }
}

// ---------------------------------------------------------------------------
// Wo (O,C,3,3) f32 -> Wt (tap, O, C) bf16
// ---------------------------------------------------------------------------
__global__ __launch_bounds__(256) void wt_prep_kernel(
    const float* __restrict__ Wo, __hip_bfloat16* __restrict__ Wt)
{
    int o = blockIdx.x;
    int c = threadIdx.x;
    const float* src = &Wo[(size_t)(o * 256 + c) * 9];
#pragma unroll
    for (int tap = 0; tap < 9; ++tap)
        Wt[(size_t)(tap * 256 + o) * 256 + c] = __float2bfloat16(src[tap]);
}

// ---------------------------------------------------------------------------
// MFMA flash attention. att written bf16 (B, N, C) pixel-major.
// ---------------------------------------------------------------------------
__global__ __launch_bounds__(512) void flash_mfma_kernel(
    const __hip_bfloat16* __restrict__ qg, const __hip_bfloat16* __restrict__ kg,
    const __hip_bfloat16* __restrict__ vg, __hip_bfloat16* __restrict__ att)
{
    __shared__ __hip_bfloat16 v_lds[256 * 72];   // [c][key] stride 72
    __shared__ __hip_bfloat16 p_lds[64 * 72];    // [q][key]  stride 72
    __shared__ float corr_lds[64];
    __shared__ float l_lds[64];

    int b  = blockIdx.x >> 6;
    int n0 = (blockIdx.x & 63) * 64;
    int t  = threadIdx.x;
    int w  = t >> 6, lane = t & 63;
    int l15 = lane & 15, l4 = lane >> 4;
    int qs = w & 3;
    int cw = w * 32;

    const float SC = 0.17677669529663687f * 1.4426950408889634f; // scale*log2(e)

    short8 qf = *(const short8*)&qg[((size_t)(b * N_TOK + n0 + qs * 16 + l15)) * 32 + l4 * 8];

    f32x4 zf = {0.f, 0.f, 0.f, 0.f};
    f32x4 acc[4][2];
#pragma unroll
    for (int i = 0; i < 4; ++i) { acc[i][0] = zf; acc[i][1] = zf; }
    float Mr = -3.0e38f, Lr = 0.f;

    for (int m0 = 0; m0 < N_TOK; m0 += 64) {
        {
            int c = t >> 1, half = t & 1;
            const __hip_bfloat16* src = &vg[((size_t)(b * 256 + c)) * N_TOK + m0 + half * 32];
            __hip_bfloat16* dstp = &v_lds[c * 72 + half * 32];
            short8 s0 = *(const short8*)(src);
            short8 s1 = *(const short8*)(src + 8);
            short8 s2 = *(const short8*)(src + 16);
            short8 s3 = *(const short8*)(src + 24);
            *(short8*)(dstp)      = s0;
            *(short8*)(dstp + 8)  = s1;
            *(short8*)(dstp + 16) = s2;
            *(short8*)(dstp + 24) = s3;
        }

        if (w < 4) {
            f32x4 sf[4];
#pragma unroll
            for (int kt = 0; kt < 4; ++kt) {
                short8 kf = *(const short8*)&kg[((size_t)(b * N_TOK + m0 + kt * 16 + l15)) * 32 + l4 * 8];
                sf[kt] = MFMA16(kf, qf, zf);
            }
            float smax = -3.0e38f;
#pragma unroll
            for (int kt = 0; kt < 4; ++kt)
#pragma unroll
                for (int r = 0; r < 4; ++r) smax = fmaxf(smax, sf[kt][r]);
            smax = fmaxf(smax, __shfl_xor(smax, 16));
            smax = fmaxf(smax, __shfl_xor(smax, 32));
            float newM = fmaxf(Mr, smax);
            float corr = exp2f((Mr - newM) * SC);
            float psum = 0.f;
            float pm[16];
#pragma unroll
            for (int kt = 0; kt < 4; ++kt)
#pragma unroll
                for (int r = 0; r < 4; ++r) {
                    float p = exp2f((sf[kt][r] - newM) * SC);
                    pm[kt * 4 + r] = p;
                    psum += p;
                }
            psum += __shfl_xor(psum, 16);
            psum += __shfl_xor(psum, 32);
            Lr = Lr * corr + psum;
            Mr = newM;
#pragma unroll
            for (int kt = 0; kt < 4; ++kt) {
                uint2 u;
                u.x = pack_bf16x2(pm[kt * 4 + 0], pm[kt * 4 + 1]);
                u.y = pack_bf16x2(pm[kt * 4 + 2], pm[kt * 4 + 3]);
                *(uint2*)&p_lds[(qs * 16 + l15) * 72 + kt * 16 + l4 * 4] = u;
            }
            if (l4 == 0) corr_lds[qs * 16 + l15] = corr;
        }
        __syncthreads();

        short8 vfr[2][2];
#pragma unroll
        for (int ct = 0; ct < 2; ++ct)
#pragma unroll
            for (int ks = 0; ks < 2; ++ks)
                vfr[ct][ks] = *(const short8*)&v_lds[(cw + ct * 16 + l15) * 72 + ks * 32 + l4 * 8];

#pragma unroll
        for (int qt = 0; qt < 4; ++qt) {
            float cq = corr_lds[qt * 16 + l15];
#pragma unroll
            for (int ct = 0; ct < 2; ++ct)
#pragma unroll
                for (int r = 0; r < 4; ++r) acc[qt][ct][r] *= cq;
#pragma unroll
            for (int ks = 0; ks < 2; ++ks) {
                short8 bf = *(const short8*)&p_lds[(qt * 16 + l15) * 72 + ks * 32 + l4 * 8];
                acc[qt][0] = MFMA16(vfr[0][ks], bf, acc[qt][0]);
                acc[qt][1] = MFMA16(vfr[1][ks], bf, acc[qt][1]);
            }
        }
        __syncthreads();
    }

    if (w < 4 && l4 == 0) l_lds[qs * 16 + l15] = Lr;
    __syncthreads();

    // att (B,N,C) bf16: lane has 4 consecutive c per (qt,ct)
#pragma unroll
    for (int qt = 0; qt < 4; ++qt) {
        float inv = 1.f / l_lds[qt * 16 + l15];
        size_t pix = (size_t)(b * N_TOK + n0 + qt * 16 + l15);
#pragma unroll
        for (int ct = 0; ct < 2; ++ct) {
            int c0 = cw + ct * 16 + l4 * 4;
            uint2 u;
            u.x = pack_bf16x2(acc[qt][ct][0] * inv, acc[qt][ct][1] * inv);
            u.y = pack_bf16x2(acc[qt][ct][2] * inv, acc[qt][ct][3] * inv);
            *(uint2*)&att[pix * 256 + c0] = u;
        }
    }
}

// ---------------------------------------------------------------------------
// Implicit-GEMM 3x3 conv via MFMA + bias + BN + ReLU + residual.
// Block: 256 thr = 4 waves. Tile: 64 o-ch x 16x16 pixels. K = 256c x 9 taps.
// Wave w: all 4 m-tiles (16 o each) x rows yy = w*4..w*4+3.
// ---------------------------------------------------------------------------
__global__ __launch_bounds__(256) void conv_mfma_kernel(
    const __hip_bfloat16* __restrict__ att, const __hip_bfloat16* __restrict__ Wt,
    const float* __restrict__ bo,  const float* __restrict__ gamma,
    const float* __restrict__ beta, const float* __restrict__ mean,
    const float* __restrict__ var, const float* __restrict__ x,
    float* __restrict__ out)
{
    __shared__ __hip_bfloat16 in_lds[324 * 32];     // swizzled [halo-pix][32c]
    __shared__ __hip_bfloat16 wt_lds[9 * 64 * 32];  // swizzled [tap][o64][32c]

    int blk = blockIdx.x;
    int sp = blk & 15, ob = (blk >> 4) & 3, b = blk >> 6;
    int y0 = (sp >> 2) * 16, x0 = (sp & 3) * 16;
    int o0 = ob * 64;
    int t = threadIdx.x;
    int w = t >> 6, lane = t & 63;
    int l15 = lane & 15, l4 = lane >> 4;

    f32x4 zf = {0.f, 0.f, 0.f, 0.f};
    f32x4 acc[4][4];   // [m][ntw]
#pragma unroll
    for (int m = 0; m < 4; ++m)
#pragma unroll
        for (int n = 0; n < 4; ++n) acc[m][n] = zf;

    for (int cc = 0; cc < 256; cc += 32) {
        __syncthreads();
        // ---- stage input halo: 324 pixels x 32c (16B chunks, swizzled)
        for (int jj = t; jj < 1296; jj += 256) {
            int pix = jj >> 2, h = jj & 3;
            int iy = pix / 18, ix = pix - iy * 18;
            int gy = y0 - 1 + iy, gx = x0 - 1 + ix;
            uint4 val = {0u, 0u, 0u, 0u};
            if (gy >= 0 && gy < 64 && gx >= 0 && gx < 64)
                val = *(const uint4*)&att[((size_t)(b * N_TOK + gy * 64 + gx)) * 256 + cc + h * 8];
            *(uint4*)&in_lds[pix * 32 + swz4(h, pix) * 8] = val;
        }
        // ---- stage weights: 9 taps x 64 o x 32 c
        for (int jj = t; jj < 2304; jj += 256) {
            int tap = jj >> 8, rem = jj & 255;
            int o = rem >> 2, h = rem & 3;
            uint4 wv = *(const uint4*)&Wt[((size_t)(tap * 256 + o0 + o)) * 256 + cc + h * 8];
            *(uint4*)&wt_lds[tap * 2048 + o * 32 + swz4(h, o) * 8] = wv;
        }
        __syncthreads();

#pragma unroll
        for (int ky = 0; ky < 3; ++ky) {
#pragma unroll
            for (int kx = 0; kx < 3; ++kx) {
                int tap = ky * 3 + kx;
                short8 af[4];
#pragma unroll
                for (int m = 0; m < 4; ++m) {
                    int orow = m * 16 + l15;
                    af[m] = *(const short8*)&wt_lds[tap * 2048 + orow * 32 + swz4(l4, orow) * 8];
                }
#pragma unroll
                for (int ntw = 0; ntw < 4; ++ntw) {
                    int yy = w * 4 + ntw;
                    int p = (yy + ky) * 18 + kx + l15;
                    short8 bfr = *(const short8*)&in_lds[p * 32 + swz4(l4, p) * 8];
#pragma unroll
                    for (int m = 0; m < 4; ++m)
                        acc[m][ntw] = MFMA16(af[m], bfr, acc[m][ntw]);
                }
            }
        }
    }

    // ---- epilogue: bias + BN + ReLU + residual
#pragma unroll
    for (int m = 0; m < 4; ++m) {
#pragma unroll
        for (int r = 0; r < 4; ++r) {
            int oc = o0 + m * 16 + l4 * 4 + r;
            float inv = gamma[oc] * rsqrtf(var[oc] + 1e-5f);
            float sh  = (bo[oc] - mean[oc]) * inv + beta[oc];
#pragma unroll
            for (int ntw = 0; ntw < 4; ++ntw) {
                int gy = y0 + w * 4 + ntw, gx = x0 + l15;
                size_t idx = (size_t)(b * 256 + oc) * 4096 + (size_t)gy * 64 + gx;
                float yv = acc[m][ntw][r] * inv + sh;
                yv = fmaxf(yv, 0.f);
                out[idx] = yv + x[idx];
            }
        }
    }
}

// ---------------------------------------------------------------------------
extern "C" void kernel_launch(void* const* d_in, const int* in_sizes, int n_in,
                              void* d_out, int out_size, void* d_ws, size_t ws_size,
                              hipStream_t stream)
{
    const float* x  = (const float*)d_in[0];
    const float* Wq = (const float*)d_in[1];
    const float* bq = (const float*)d_in[2];
    const float* Wk = (const float*)d_in[3];
    const float* bk = (const float*)d_in[4];
    const float* Wv = (const float*)d_in[5];
    const float* bv = (const float*)d_in[6];
    const float* Wo = (const float*)d_in[7];
    const float* bo = (const float*)d_in[8];
    const float* gm = (const float*)d_in[9];
    const float* bt = (const float*)d_in[10];
    const float* mn = (const float*)d_in[11];
    const float* vr = (const float*)d_in[12];
    float* out = (float*)d_out;

    char* wsb = (char*)d_ws;
    __hip_bfloat16* qg  = (__hip_bfloat16*)(wsb);                 // 1 MB
    __hip_bfloat16* kg  = (__hip_bfloat16*)(wsb + (1u << 20));    // 1 MB
    __hip_bfloat16* vg  = (__hip_bfloat16*)(wsb + (2u << 20));    // 8 MB
    __hip_bfloat16* att = (__hip_bfloat16*)(wsb + (10u << 20));   // 8 MB
    __hip_bfloat16* Wt  = (__hip_bfloat16*)(wsb + (18u << 20));   // 1.2 MB

    wt_prep_kernel  <<<256,  256, 0, stream>>>(Wo, Wt);
    qk_proj_kernel  <<<512,  256, 0, stream>>>(x, Wq, bq, Wk, bk, qg, kg);
    v_proj_kernel   <<<512,  256, 0, stream>>>(x, Wv, bv, vg);
    flash_mfma_kernel<<<256, 512, 0, stream>>>(qg, kg, vg, att);
    conv_mfma_kernel<<<256,  256, 0, stream>>>(att, Wt, bo, gm, bt, mn, vr, x, out);
}